// Round 4
// baseline (421.796 us; speedup 1.0000x reference)
//
#include <hip/hip_runtime.h>
#include <stdint.h>
#include <stddef.h>

#define B_SZ   2048
#define E_SZ   96
#define K_SZ   8
#define U_SZ   1024
#define EK     (E_SZ * K_SZ)           /* 768  */
#define KD     ((E_SZ + U_SZ) * K_SZ)  /* 8960 */
#define NZ     (4 * U_SZ)              /* 4096 */

typedef _Float16 f16_t;
typedef _Float16 f16x8 __attribute__((ext_vector_type(8)));
typedef float    f32x4  __attribute__((ext_vector_type(4)));
typedef float    f32x16 __attribute__((ext_vector_type(16)));

typedef __attribute__((address_space(3))) void       lds_void;
typedef const __attribute__((address_space(1))) void gbl_void;

__device__ __forceinline__ void gload16(const void* g, void* l) {
    __builtin_amdgcn_global_load_lds((gbl_void*)g, (lds_void*)l, 16, 0, 0);
}

// ---------------- pass 1: A = [x (x) cp | h (x) cp] -> f16 ----------------
__global__ __launch_bounds__(256) void build_a_kernel(
    const float* __restrict__ inputs,   // (B, 104)
    const float* __restrict__ h_tm1,    // (B, 1024)
    f16_t* __restrict__ Ah)
{
    unsigned tid = blockIdx.x * 256u + threadIdx.x;   // exactly 2048*1120
    unsigned b   = tid / 1120u;
    unsigned i8  = tid - b * 1120u;

    const float* row = inputs + (size_t)b * (E_SZ + K_SZ);
    f32x4 cp0 = *(const f32x4*)(row + E_SZ);
    f32x4 cp1 = *(const f32x4*)(row + E_SZ + 4);
    float cp[8] = {cp0[0], cp0[1], cp0[2], cp0[3], cp1[0], cp1[1], cp1[2], cp1[3]};

    float base = (i8 < (unsigned)E_SZ) ? row[i8]
                                       : h_tm1[(size_t)b * U_SZ + (i8 - E_SZ)];
    f16x8 hi;
    #pragma unroll
    for (int k = 0; k < 8; ++k)
        hi[k] = (f16_t)(base * cp[k]);
    *(f16x8*)(Ah + (size_t)b * KD + (size_t)i8 * 8) = hi;
}

// ---------------- pass 2: W (8960 x 4096 f32) -> W^T f16 (4096 x 8960) ----------------
__global__ __launch_bounds__(256) void transpose_w_kernel(
    const float* __restrict__ bk,    // (768, 4096)
    const float* __restrict__ brk,   // (8192, 4096)
    f16_t* __restrict__ Wth)
{
    __shared__ float tile[64][65];
    int r0 = blockIdx.x * 64;        // 140 tiles along K (768 % 64 == 0, no straddle)
    int z0 = blockIdx.y * 64;
    const float* src = (r0 < EK) ? (bk + (size_t)r0 * NZ)
                                 : (brk + (size_t)(r0 - EK) * NZ);
    int t  = threadIdx.x;
    int rl = t >> 4;
    int c4 = (t & 15) * 4;

    #pragma unroll
    for (int i = 0; i < 4; ++i) {
        int r = rl + i * 16;
        f32x4 v = *(const f32x4*)(src + (size_t)r * NZ + z0 + c4);
        tile[r][c4 + 0] = v[0];
        tile[r][c4 + 1] = v[1];
        tile[r][c4 + 2] = v[2];
        tile[r][c4 + 3] = v[3];
    }
    __syncthreads();
    int zl = t >> 3;             // 0..31
    int c8 = (t & 7) * 8;        // 0..56
    #pragma unroll
    for (int i = 0; i < 2; ++i) {
        int z = zl + i * 32;
        f16x8 hi;
        #pragma unroll
        for (int j = 0; j < 8; ++j)
            hi[j] = (f16_t)tile[c8 + j][z];   // 2-way bank max (free)
        *(f16x8*)(Wth + (size_t)(z0 + z) * KD + r0 + c8) = hi;
    }
}

// ---------------- pass 3: f16 GEMM (32x32x16 MFMA, 4-buffer counted-vmcnt) ----------------
// BM=256 x BN=128 (32 j * 4 gates), BK=32, 8 waves 4m x 2n, wave tile 64x64 = 2x2 frags.
// 4 circular LDS buffers (24 KB each), stage 3 tiles ahead, 3 gloads/thread/tile,
// steady-state s_waitcnt vmcnt(6). Epilogue: z via LDS roundtrip, fused LSTM.
#define BM 256
#define BN 128
#define BK 32
#define NT 280                      /* 8960/32 */
#define ABY (BM * BK * 2)           /* 16384 */
#define WBY (BN * BK * 2)           /* 8192  */
#define BUFB (ABY + WBY)            /* 24576 */
#define SMEM_BYTES 131072           /* max(4*BUFB=98304, 256*128*4=131072) */

__global__ __launch_bounds__(512, 2) void basis_lstm_gemm_kernel(
    const f16_t* __restrict__ Ah, const f16_t* __restrict__ Wth,
    const float* __restrict__ bias, const float* __restrict__ c_tm1,
    float* __restrict__ out)
{
    extern __shared__ __align__(16) char smem[];

    // XCD swizzle: each XCD gets 4 jb values x all 8 bm (W slice ~9 MB, A via L3)
    int id  = blockIdx.x;
    int v   = (id & 7) * 32 + (id >> 3);
    int bm0 = (v & 7) * BM;
    int jb0 = (v >> 3) * 32;        // 32 j-columns per block

    int t    = threadIdx.x;
    int lane = t & 63;
    int w    = t >> 6;
    int wm   = w >> 1;              // 0..3 -> rows [wm*64, +64)
    int wn   = w & 1;               // 0..1 -> cols [wn*64, +64)
    int l31  = lane & 31;
    int lh   = lane >> 5;           // 0/1 -> k-half of the 32x32x16 fragment

    f32x16 acc[2][2];
    #pragma unroll
    for (int mi = 0; mi < 2; ++mi)
        #pragma unroll
        for (int ni = 0; ni < 2; ++ni)
            #pragma unroll
            for (int e = 0; e < 16; ++e)
                acc[mi][ni][e] = 0.f;

    // rows are 64 B = 4 chunks of 16 B; LDS slot (row, cc) holds global chunk cc ^ swz(row)
    // swz(r) = (r ^ (r>>2)) & 3  -> per-16-lane frag reads are 2-way max (free)
    auto stageA = [&](int kt) {               // 2 gloads
        char* buf = smem + (kt & 3) * BUFB;
        int   ko  = kt * BK;
        #pragma unroll
        for (int i = 0; i < 2; ++i) {
            int q = i * 512 + t;              // 0..1023
            int row = q >> 2, cc = q & 3;
            size_t off = (size_t)(bm0 + row) * KD + ko + ((cc ^ ((row ^ (row >> 2)) & 3)) << 3);
            gload16(Ah + off, buf + q * 16);
        }
    };
    auto stageB = [&](int kt) {               // 1 gload
        char* buf = smem + (kt & 3) * BUFB + ABY;
        int   ko  = kt * BK;
        int q = t, c = q >> 2, cc = q & 3;    // c = block col 0..127
        int z = ((c >> 5) << 10) + jb0 + (c & 31);
        size_t off = (size_t)z * KD + ko + ((cc ^ ((c ^ (c >> 2)) & 3)) << 3);
        gload16(Wth + off, buf + q * 16);
    };

    // one phase: frag reads (k-slot ks) || stage -> barrier -> prio(1) 4 MFMA prio(0)
    auto phase = [&](int kt, int ks, int stg) {
        const char* buf = smem + (kt & 3) * BUFB;
        f16x8 af[2], wf[2];
        #pragma unroll
        for (int mi = 0; mi < 2; ++mi) {
            int r  = wm * 64 + mi * 32 + l31;
            int sc = (ks * 2 + lh) ^ ((r ^ (r >> 2)) & 3);
            af[mi] = *(const f16x8*)(buf + r * 64 + sc * 16);
        }
        #pragma unroll
        for (int ni = 0; ni < 2; ++ni) {
            int r  = wn * 64 + ni * 32 + l31;
            int sc = (ks * 2 + lh) ^ ((r ^ (r >> 2)) & 3);
            wf[ni] = *(const f16x8*)(buf + ABY + r * 64 + sc * 16);
        }
        if (stg == 1) stageA(kt + 3);
        else if (stg == 2) stageB(kt + 3);
        __builtin_amdgcn_s_barrier();
        __builtin_amdgcn_s_setprio(1);
        #pragma unroll
        for (int mi = 0; mi < 2; ++mi)
            #pragma unroll
            for (int ni = 0; ni < 2; ++ni)
                acc[mi][ni] = __builtin_amdgcn_mfma_f32_32x32x16_f16(af[mi], wf[ni], acc[mi][ni], 0, 0, 0);
        __builtin_amdgcn_s_setprio(0);
    };

    // prologue: 3 tiles in flight (9 loads); wait tile 0 (keep 6 outstanding)
    stageA(0); stageB(0);
    stageA(1); stageB(1);
    stageA(2); stageB(2);
    asm volatile("s_waitcnt vmcnt(6)" ::: "memory");
    __builtin_amdgcn_s_barrier();

    for (int kt = 0; kt < NT - 3; ++kt) {
        phase(kt, 0, 1);
        __builtin_amdgcn_s_barrier();
        phase(kt, 1, 2);
        asm volatile("s_waitcnt vmcnt(6)" ::: "memory");   // tile kt+1 landed
        __builtin_amdgcn_s_barrier();
    }
    phase(NT - 3, 0, 0); __builtin_amdgcn_s_barrier();
    phase(NT - 3, 1, 0);
    asm volatile("s_waitcnt vmcnt(3)" ::: "memory");
    __builtin_amdgcn_s_barrier();
    phase(NT - 2, 0, 0); __builtin_amdgcn_s_barrier();
    phase(NT - 2, 1, 0);
    asm volatile("s_waitcnt vmcnt(0)" ::: "memory");
    __builtin_amdgcn_s_barrier();
    phase(NT - 1, 0, 0); __builtin_amdgcn_s_barrier();
    phase(NT - 1, 1, 0);
    __syncthreads();

    // ---- epilogue: z roundtrip through LDS (gates live in different waves) ----
    // C/D 32x32: row = (reg&3) + 8*(reg>>2) + 4*lh, col = l31
    float* zb = (float*)smem;
    #pragma unroll
    for (int mi = 0; mi < 2; ++mi)
        #pragma unroll
        for (int ni = 0; ni < 2; ++ni)
            #pragma unroll
            for (int r = 0; r < 16; ++r) {
                int row = wm * 64 + mi * 32 + (r & 3) + 8 * (r >> 2) + 4 * lh;
                int col = wn * 64 + ni * 32 + l31;
                zb[row * 128 + col] = acc[mi][ni][r];
            }
    __syncthreads();

    int jj = t & 31;
    int rg = t >> 5;                 // 0..15 -> rows [rg*16, +16)
    int jg = jb0 + jj;
    float b0 = bias[jg];
    float b1 = bias[U_SZ + jg];
    float b2 = bias[2 * U_SZ + jg];
    float b3 = bias[3 * U_SZ + jg];
    float* out_h = out;
    float* out_c = out + (size_t)B_SZ * U_SZ;
    #pragma unroll
    for (int i = 0; i < 16; ++i) {
        int   row = rg * 16 + i;
        int   br  = bm0 + row;
        float zi = zb[row * 128 +  0 + jj] + b0;
        float zf = zb[row * 128 + 32 + jj] + b1;
        float zc = zb[row * 128 + 64 + jj] + b2;
        float zo = zb[row * 128 + 96 + jj] + b3;
        float ig = 1.f / (1.f + __expf(-zi));
        float fg = 1.f / (1.f + __expf(-zf));
        float og = 1.f / (1.f + __expf(-zo));
        float cn = fg * c_tm1[(size_t)br * U_SZ + jg] + ig * tanhf(zc);
        float hn = og * tanhf(cn);
        out_h[(size_t)br * U_SZ + jg] = hn;
        out_c[(size_t)br * U_SZ + jg] = cn;
    }
}

extern "C" void kernel_launch(void* const* d_in, const int* in_sizes, int n_in,
                              void* d_out, int out_size, void* d_ws, size_t ws_size,
                              hipStream_t stream) {
    const float* inputs = (const float*)d_in[0];
    const float* h_tm1  = (const float*)d_in[1];
    const float* c_tm1  = (const float*)d_in[2];
    const float* bk     = (const float*)d_in[3];
    const float* brk    = (const float*)d_in[4];
    const float* bias   = (const float*)d_in[5];

    // workspace: Ah 36,700,160 B | Wth 73,400,320 B  (total 110 MB)
    char*  ws  = (char*)d_ws;
    f16_t* Ah  = (f16_t*)(ws);
    f16_t* Wth = (f16_t*)(ws + 36700160u);

    hipFuncSetAttribute((const void*)basis_lstm_gemm_kernel,
                        hipFuncAttributeMaxDynamicSharedMemorySize, SMEM_BYTES);

    hipLaunchKernelGGL(build_a_kernel, dim3(8960), dim3(256), 0, stream,
                       inputs, h_tm1, Ah);
    hipLaunchKernelGGL(transpose_w_kernel, dim3(140, 64), dim3(256), 0, stream,
                       bk, brk, Wth);
    hipLaunchKernelGGL(basis_lstm_gemm_kernel, dim3(256), dim3(512), SMEM_BYTES, stream,
                       Ah, Wth, bias, c_tm1, (float*)d_out);
}

// Round 5
// 418.133 us; speedup vs baseline: 1.0088x; 1.0088x over previous
//
#include <hip/hip_runtime.h>
#include <stdint.h>
#include <stddef.h>

#define B_SZ   2048
#define E_SZ   96
#define K_SZ   8
#define U_SZ   1024
#define EK     (E_SZ * K_SZ)           /* 768  */
#define KD     ((E_SZ + U_SZ) * K_SZ)  /* 8960 */
#define NZ     (4 * U_SZ)              /* 4096 */

typedef _Float16 f16_t;
typedef _Float16 f16x8 __attribute__((ext_vector_type(8)));
typedef float    f32x4  __attribute__((ext_vector_type(4)));
typedef float    f32x16 __attribute__((ext_vector_type(16)));

typedef __attribute__((address_space(3))) void       lds_void;
typedef const __attribute__((address_space(1))) void gbl_void;

__device__ __forceinline__ void gload16(const void* g, void* l) {
    __builtin_amdgcn_global_load_lds((gbl_void*)g, (lds_void*)l, 16, 0, 0);
}

// ---------------- pass 1: A = [x (x) cp | h (x) cp] -> f16 ----------------
__global__ __launch_bounds__(256) void build_a_kernel(
    const float* __restrict__ inputs,   // (B, 104)
    const float* __restrict__ h_tm1,    // (B, 1024)
    f16_t* __restrict__ Ah)
{
    unsigned tid = blockIdx.x * 256u + threadIdx.x;   // exactly 2048*1120
    unsigned b   = tid / 1120u;
    unsigned i8  = tid - b * 1120u;

    const float* row = inputs + (size_t)b * (E_SZ + K_SZ);
    f32x4 cp0 = *(const f32x4*)(row + E_SZ);
    f32x4 cp1 = *(const f32x4*)(row + E_SZ + 4);
    float cp[8] = {cp0[0], cp0[1], cp0[2], cp0[3], cp1[0], cp1[1], cp1[2], cp1[3]};

    float base = (i8 < (unsigned)E_SZ) ? row[i8]
                                       : h_tm1[(size_t)b * U_SZ + (i8 - E_SZ)];
    f16x8 hi;
    #pragma unroll
    for (int k = 0; k < 8; ++k)
        hi[k] = (f16_t)(base * cp[k]);
    *(f16x8*)(Ah + (size_t)b * KD + (size_t)i8 * 8) = hi;
}

// ---------------- pass 2: W (8960 x 4096 f32) -> W^T f16 (4096 x 8960) ----------------
__global__ __launch_bounds__(256) void transpose_w_kernel(
    const float* __restrict__ bk,    // (768, 4096)
    const float* __restrict__ brk,   // (8192, 4096)
    f16_t* __restrict__ Wth)
{
    __shared__ float tile[64][65];
    int r0 = blockIdx.x * 64;        // 140 tiles along K (768 % 64 == 0, no straddle)
    int z0 = blockIdx.y * 64;
    const float* src = (r0 < EK) ? (bk + (size_t)r0 * NZ)
                                 : (brk + (size_t)(r0 - EK) * NZ);
    int t  = threadIdx.x;
    int rl = t >> 4;
    int c4 = (t & 15) * 4;

    #pragma unroll
    for (int i = 0; i < 4; ++i) {
        int r = rl + i * 16;
        f32x4 v = *(const f32x4*)(src + (size_t)r * NZ + z0 + c4);
        tile[r][c4 + 0] = v[0];
        tile[r][c4 + 1] = v[1];
        tile[r][c4 + 2] = v[2];
        tile[r][c4 + 3] = v[3];
    }
    __syncthreads();
    int zl = t >> 3;             // 0..31
    int c8 = (t & 7) * 8;        // 0..56
    #pragma unroll
    for (int i = 0; i < 2; ++i) {
        int z = zl + i * 32;
        f16x8 hi;
        #pragma unroll
        for (int j = 0; j < 8; ++j)
            hi[j] = (f16_t)tile[c8 + j][z];   // 2-way bank max (free)
        *(f16x8*)(Wth + (size_t)(z0 + z) * KD + r0 + c8) = hi;
    }
}

// ---------------- pass 3: f16 GEMM, BM=BN=256, split-K2 across blocks ----------------
// 8 waves (2m x 4n), wave tile 128x64 (4x2 32x32 frags), BK=32, 4-deep buffers,
// counted vmcnt(8), one barrier per K-tile. Writes f32 partial z to zpart[kh].
#define BM 256
#define BN 256                      /* 64 j * 4 gates */
#define BK 32
#define KHALF 4480
#define NT 140                      /* 4480/32 */
#define ABY (BM * BK * 2)           /* 16384 */
#define WBY (BN * BK * 2)           /* 16384 */
#define BUFB (ABY + WBY)            /* 32768 */
#define SMEM_BYTES (4 * BUFB)       /* 131072 */

__global__ __launch_bounds__(512, 2) void basis_lstm_gemm_kernel(
    const f16_t* __restrict__ Ah, const f16_t* __restrict__ Wth,
    float* __restrict__ zpart)
{
    extern __shared__ __align__(16) char smem[];

    // XCD-aware: xcd = id&7 (round-robin dispatch); each XCD: 2 jb x 8 bm x 2 kh
    int id   = blockIdx.x;
    int xcd  = id & 7;
    int rest = id >> 3;              // 0..31
    int kh   = rest & 1;
    int bm0  = ((rest >> 1) & 7) * BM;
    int jb   = xcd * 2 + (rest >> 4);        // 0..15, 64 j's each
    int kbase = kh * KHALF;
    float* zp = zpart + (size_t)kh * B_SZ * NZ;

    int t    = threadIdx.x;
    int lane = t & 63;
    int w    = t >> 6;
    int wm   = w & 1;               // rows [wm*128, +128)
    int wn   = w >> 1;              // cols [wn*64, +64)
    int l31  = lane & 31;
    int lh   = lane >> 5;

    f32x16 acc[4][2];
    #pragma unroll
    for (int mi = 0; mi < 4; ++mi)
        #pragma unroll
        for (int ni = 0; ni < 2; ++ni)
            #pragma unroll
            for (int e = 0; e < 16; ++e)
                acc[mi][ni][e] = 0.f;

    // rows are 64 B = 4 chunks; LDS slot (row, cc) holds global chunk cc ^ swz(row),
    // swz(r) = (r ^ (r>>2)) & 3  (per-16-lane reads 2-way max = free; verified 0-conflict)
    auto stage = [&](int kt) {
        char* buf = smem + (kt & 3) * BUFB;
        int   ko  = kbase + kt * BK;
        #pragma unroll
        for (int i = 0; i < 2; ++i) {
            int q = i * 512 + t;              // 0..1023
            int row = q >> 2, cc = q & 3;
            size_t off = (size_t)(bm0 + row) * KD + ko + ((cc ^ ((row ^ (row >> 2)) & 3)) << 3);
            gload16(Ah + off, buf + q * 16);
        }
        #pragma unroll
        for (int i = 0; i < 2; ++i) {
            int q = i * 512 + t;              // 0..1023
            int c = q >> 2, cc = q & 3;
            int z = ((c >> 6) << 10) + jb * 64 + (c & 63);
            size_t off = (size_t)z * KD + ko + ((cc ^ ((c ^ (c >> 2)) & 3)) << 3);
            gload16(Wth + off, buf + ABY + q * 16);
        }
    };

    auto cslice = [&](const char* buf, int ks) {
        f16x8 af[4], wf[2];
        #pragma unroll
        for (int mi = 0; mi < 4; ++mi) {
            int r  = wm * 128 + mi * 32 + l31;
            int sc = (ks * 2 + lh) ^ ((r ^ (r >> 2)) & 3);
            af[mi] = *(const f16x8*)(buf + r * 64 + sc * 16);
        }
        #pragma unroll
        for (int ni = 0; ni < 2; ++ni) {
            int c  = wn * 64 + ni * 32 + l31;
            int sc = (ks * 2 + lh) ^ ((c ^ (c >> 2)) & 3);
            wf[ni] = *(const f16x8*)(buf + ABY + c * 64 + sc * 16);
        }
        __builtin_amdgcn_s_setprio(1);
        #pragma unroll
        for (int mi = 0; mi < 4; ++mi)
            #pragma unroll
            for (int ni = 0; ni < 2; ++ni)
                acc[mi][ni] = __builtin_amdgcn_mfma_f32_32x32x16_f16(af[mi], wf[ni], acc[mi][ni], 0, 0, 0);
        __builtin_amdgcn_s_setprio(0);
    };

    stage(0); stage(1); stage(2);
    asm volatile("s_waitcnt vmcnt(8)" ::: "memory");   // tile 0 landed (t1,t2 in flight)
    __builtin_amdgcn_s_barrier();

    #pragma unroll 1
    for (int kt = 0; kt < NT; ++kt) {
        if (kt + 3 < NT) stage(kt + 3);
        const char* buf = smem + (kt & 3) * BUFB;
        cslice(buf, 0);
        cslice(buf, 1);
        if (kt <= NT - 4) {
            asm volatile("s_waitcnt vmcnt(8)" ::: "memory");   // tile kt+1 landed
        } else if (kt == NT - 3) {
            asm volatile("s_waitcnt vmcnt(4)" ::: "memory");
        } else if (kt == NT - 2) {
            asm volatile("s_waitcnt vmcnt(0)" ::: "memory");
        }
        if (kt < NT - 1) __builtin_amdgcn_s_barrier();
    }

    // ---- store f32 partial tile (C/D 32x32: col=l31, row=(reg&3)+8*(reg>>2)+4*lh)
    #pragma unroll
    for (int ni = 0; ni < 2; ++ni) {
        int c    = wn * 64 + ni * 32 + l31;
        int zcol = ((c >> 6) << 10) + jb * 64 + (c & 63);
        #pragma unroll
        for (int mi = 0; mi < 4; ++mi) {
            #pragma unroll
            for (int r = 0; r < 16; ++r) {
                int row = wm * 128 + mi * 32 + (r & 3) + 8 * (r >> 2) + 4 * lh;
                zp[(size_t)(bm0 + row) * NZ + zcol] = acc[mi][ni][r];
            }
        }
    }
}

// ---------------- pass 4: z = zp0 + zp1 + bias, fused LSTM ----------------
__global__ __launch_bounds__(256) void lstm_reduce_kernel(
    const float* __restrict__ zpart, const float* __restrict__ bias,
    const float* __restrict__ c_tm1, float* __restrict__ out)
{
    int b  = blockIdx.x;
    int j4 = threadIdx.x * 4;
    const float* zp0 = zpart + (size_t)b * NZ;
    const float* zp1 = zpart + (size_t)B_SZ * NZ + (size_t)b * NZ;

    f32x4 zg[4];
    #pragma unroll
    for (int g = 0; g < 4; ++g) {
        f32x4 a = *(const f32x4*)(zp0 + g * U_SZ + j4);
        f32x4 c = *(const f32x4*)(zp1 + g * U_SZ + j4);
        f32x4 bb = *(const f32x4*)(bias + g * U_SZ + j4);
        zg[g] = a + c + bb;
    }
    f32x4 cprev = *(const f32x4*)(c_tm1 + (size_t)b * U_SZ + j4);
    f32x4 ho, co;
    #pragma unroll
    for (int e = 0; e < 4; ++e) {
        float ig = 1.f / (1.f + __expf(-zg[0][e]));
        float fg = 1.f / (1.f + __expf(-zg[1][e]));
        float og = 1.f / (1.f + __expf(-zg[3][e]));
        float cn = fg * cprev[e] + ig * tanhf(zg[2][e]);
        co[e] = cn;
        ho[e] = og * tanhf(cn);
    }
    *(f32x4*)(out + (size_t)b * U_SZ + j4) = ho;
    *(f32x4*)(out + (size_t)B_SZ * U_SZ + (size_t)b * U_SZ + j4) = co;
}

extern "C" void kernel_launch(void* const* d_in, const int* in_sizes, int n_in,
                              void* d_out, int out_size, void* d_ws, size_t ws_size,
                              hipStream_t stream) {
    const float* inputs = (const float*)d_in[0];
    const float* h_tm1  = (const float*)d_in[1];
    const float* c_tm1  = (const float*)d_in[2];
    const float* bk     = (const float*)d_in[3];
    const float* brk    = (const float*)d_in[4];
    const float* bias   = (const float*)d_in[5];

    // ws: Ah 36,700,160 | Wth 73,400,320 | zpart 2*33,554,432  (total ~177 MB)
    char*  ws    = (char*)d_ws;
    f16_t* Ah    = (f16_t*)(ws);
    f16_t* Wth   = (f16_t*)(ws + 36700160u);
    float* zpart = (float*)(ws + 36700160u + 73400320u);

    hipFuncSetAttribute((const void*)basis_lstm_gemm_kernel,
                        hipFuncAttributeMaxDynamicSharedMemorySize, SMEM_BYTES);

    hipLaunchKernelGGL(build_a_kernel, dim3(8960), dim3(256), 0, stream,
                       inputs, h_tm1, Ah);
    hipLaunchKernelGGL(transpose_w_kernel, dim3(140, 64), dim3(256), 0, stream,
                       bk, brk, Wth);
    hipLaunchKernelGGL(basis_lstm_gemm_kernel, dim3(256), dim3(512), SMEM_BYTES, stream,
                       Ah, Wth, zpart);
    hipLaunchKernelGGL(lstm_reduce_kernel, dim3(B_SZ), dim3(256), 0, stream,
                       zpart, bias, c_tm1, (float*)d_out);
}

// Round 6
// 409.887 us; speedup vs baseline: 1.0291x; 1.0201x over previous
//
#include <hip/hip_runtime.h>
#include <stdint.h>
#include <stddef.h>

#define B_SZ   2048
#define E_SZ   96
#define K_SZ   8
#define U_SZ   1024
#define EK     (E_SZ * K_SZ)           /* 768  */
#define KD     ((E_SZ + U_SZ) * K_SZ)  /* 8960 */
#define NZ     (4 * U_SZ)              /* 4096 */

typedef _Float16 f16_t;
typedef _Float16 f16x8 __attribute__((ext_vector_type(8)));
typedef float    f32x4  __attribute__((ext_vector_type(4)));
typedef float    f32x16 __attribute__((ext_vector_type(16)));

typedef __attribute__((address_space(3))) void       lds_void;
typedef const __attribute__((address_space(1))) void gbl_void;

__device__ __forceinline__ void gload16(const void* g, void* l) {
    __builtin_amdgcn_global_load_lds((gbl_void*)g, (lds_void*)l, 16, 0, 0);
}

// ---------------- pass 1: A = [x (x) cp | h (x) cp] -> f16 ----------------
__global__ __launch_bounds__(256) void build_a_kernel(
    const float* __restrict__ inputs,   // (B, 104)
    const float* __restrict__ h_tm1,    // (B, 1024)
    f16_t* __restrict__ Ah)
{
    unsigned tid = blockIdx.x * 256u + threadIdx.x;   // exactly 2048*1120
    unsigned b   = tid / 1120u;
    unsigned i8  = tid - b * 1120u;

    const float* row = inputs + (size_t)b * (E_SZ + K_SZ);
    f32x4 cp0 = *(const f32x4*)(row + E_SZ);
    f32x4 cp1 = *(const f32x4*)(row + E_SZ + 4);
    float cp[8] = {cp0[0], cp0[1], cp0[2], cp0[3], cp1[0], cp1[1], cp1[2], cp1[3]};

    float base = (i8 < (unsigned)E_SZ) ? row[i8]
                                       : h_tm1[(size_t)b * U_SZ + (i8 - E_SZ)];
    f16x8 hi;
    #pragma unroll
    for (int k = 0; k < 8; ++k)
        hi[k] = (f16_t)(base * cp[k]);
    *(f16x8*)(Ah + (size_t)b * KD + (size_t)i8 * 8) = hi;
}

// ---------------- pass 2: W (8960 x 4096 f32) -> W^T f16 (4096 x 8960) ----------------
__global__ __launch_bounds__(256) void transpose_w_kernel(
    const float* __restrict__ bk,    // (768, 4096)
    const float* __restrict__ brk,   // (8192, 4096)
    f16_t* __restrict__ Wth)
{
    __shared__ float tile[64][65];
    int r0 = blockIdx.x * 64;        // 140 tiles along K (768 % 64 == 0, no straddle)
    int z0 = blockIdx.y * 64;
    const float* src = (r0 < EK) ? (bk + (size_t)r0 * NZ)
                                 : (brk + (size_t)(r0 - EK) * NZ);
    int t  = threadIdx.x;
    int rl = t >> 4;
    int c4 = (t & 15) * 4;

    #pragma unroll
    for (int i = 0; i < 4; ++i) {
        int r = rl + i * 16;
        f32x4 v = *(const f32x4*)(src + (size_t)r * NZ + z0 + c4);
        tile[r][c4 + 0] = v[0];
        tile[r][c4 + 1] = v[1];
        tile[r][c4 + 2] = v[2];
        tile[r][c4 + 3] = v[3];
    }
    __syncthreads();
    int zl = t >> 3;             // 0..31
    int c8 = (t & 7) * 8;        // 0..56
    #pragma unroll
    for (int i = 0; i < 2; ++i) {
        int z = zl + i * 32;
        f16x8 hi;
        #pragma unroll
        for (int j = 0; j < 8; ++j)
            hi[j] = (f16_t)tile[c8 + j][z];   // 2-way bank max (free)
        *(f16x8*)(Wth + (size_t)(z0 + z) * KD + r0 + c8) = hi;
    }
}

// ---------------- pass 3: f16 GEMM, 8-phase-class schedule, split-K2 ----------------
// BM=BN=256, BK=64, 8 waves (2M x 4N), wave tile 128x64 (4x2 32x32 frags).
// 2 LDS buffers; each = {Ak0,Ak1,Bk0,Bk1} sub-tiles of [256 rows][64 B] (16 KB).
// 4 phases per K-tile = k-slices of 16; per phase: 6 ds_read_b128 || stage one
// half-tile of kt+1 (2 gloads) -> vmcnt(4) on odd phases -> s_barrier ->
// setprio(1) 8 MFMA setprio(0). Loads never drain to 0 in the main loop.
#define BM 256
#define BN 256                      /* 64 j * 4 gates */
#define BK 64
#define KHALF 4480
#define NT 70                       /* 4480/64 */
#define SUBT 16384                  /* one 256x32-k sub-tile, bytes */
#define BUFB 65536                  /* {A0,A1,B0,B1} */
#define SMEM_BYTES 131072

__global__ __launch_bounds__(512, 2) void basis_lstm_gemm_kernel(
    const f16_t* __restrict__ Ah, const f16_t* __restrict__ Wth,
    float* __restrict__ zpart)
{
    extern __shared__ __align__(16) char smem[];

    // XCD-aware: xcd = id&7 (round-robin dispatch); each XCD: 2 jb x 8 bm x 2 kh
    int id   = blockIdx.x;
    int xcd  = id & 7;
    int rest = id >> 3;              // 0..31
    int kh   = rest & 1;
    int bm0  = ((rest >> 1) & 7) * BM;
    int jb   = xcd * 2 + (rest >> 4);        // 0..15, 64 j's each
    int kbase = kh * KHALF;
    float* zp = zpart + (size_t)kh * B_SZ * NZ;

    int t    = threadIdx.x;
    int lane = t & 63;
    int w    = t >> 6;
    int wm   = w >> 2;              // 0..1 -> rows [wm*128, +128)
    int wn   = w & 3;               // 0..3 -> cols [wn*64, +64)
    int l31  = lane & 31;
    int lh   = lane >> 5;

    f32x16 acc[4][2];
    #pragma unroll
    for (int mi = 0; mi < 4; ++mi)
        #pragma unroll
        for (int ni = 0; ni < 2; ++ni)
            #pragma unroll
            for (int e = 0; e < 16; ++e)
                acc[mi][ni][e] = 0.f;

    // sub-tile rows are 64 B = 4 chunks of 16 B; LDS slot (row, cl) holds global
    // chunk cl ^ swz4(row), swz4(r) = (r ^ (r>>2)) & 3  (measured 0-conflict in R5)
    // stage halves: s=0 -> Ak0, s=1 -> Bk0, s=2 -> Ak1, s=3 -> Bk1 of tile kt
    auto stage_half = [&](int kt, int s) {
        char* buf = smem + (kt & 1) * BUFB;
        int   h   = s >> 1;
        int   ko  = kbase + kt * BK + h * 32;
        if (!(s & 1)) {
            char* dst = buf + h * SUBT;
            #pragma unroll
            for (int i = 0; i < 2; ++i) {
                int q = i * 512 + t;              // 0..1023
                int row = q >> 2, cl = q & 3;
                size_t off = (size_t)(bm0 + row) * KD + ko + ((cl ^ ((row ^ (row >> 2)) & 3)) << 3);
                gload16(Ah + off, dst + q * 16);
            }
        } else {
            char* dst = buf + 2 * SUBT + h * SUBT;
            #pragma unroll
            for (int i = 0; i < 2; ++i) {
                int q = i * 512 + t;              // 0..1023
                int c = q >> 2, cl = q & 3;
                int z = ((c >> 6) << 10) + jb * 64 + (c & 63);
                size_t off = (size_t)z * KD + ko + ((cl ^ ((c ^ (c >> 2)) & 3)) << 3);
                gload16(Wth + off, dst + q * 16);
            }
        }
    };

    // prologue: stage tile 0 fully; keep Ak1,Bk1 in flight
    stage_half(0, 0); stage_half(0, 1); stage_half(0, 2); stage_half(0, 3);
    asm volatile("s_waitcnt vmcnt(4)" ::: "memory");
    __builtin_amdgcn_s_barrier();
    __builtin_amdgcn_sched_barrier(0);

    #pragma unroll 1
    for (int kt = 0; kt < NT; ++kt) {
        const char* buf = smem + (kt & 1) * BUFB;
        #pragma unroll
        for (int s = 0; s < 4; ++s) {
            const char* abase = buf + (s >> 1) * SUBT;
            const char* bbase = buf + 2 * SUBT + (s >> 1) * SUBT;
            int cchunk = (s & 1) * 2 + lh;
            f16x8 af[4], wf[2];
            #pragma unroll
            for (int mi = 0; mi < 4; ++mi) {
                int r = wm * 128 + mi * 32 + l31;
                af[mi] = *(const f16x8*)(abase + r * 64 + ((cchunk ^ ((r ^ (r >> 2)) & 3)) << 4));
            }
            #pragma unroll
            for (int ni = 0; ni < 2; ++ni) {
                int c = wn * 64 + ni * 32 + l31;
                wf[ni] = *(const f16x8*)(bbase + c * 64 + ((cchunk ^ ((c ^ (c >> 2)) & 3)) << 4));
            }
            if (kt + 1 < NT) stage_half(kt + 1, s);
            if (s == 1) {
                if (kt + 1 < NT) asm volatile("s_waitcnt vmcnt(4)" ::: "memory");
                else             asm volatile("s_waitcnt vmcnt(0)" ::: "memory");
            } else if (s == 3) {
                if (kt + 1 < NT) asm volatile("s_waitcnt vmcnt(4)" ::: "memory");
            }
            __builtin_amdgcn_sched_barrier(0);
            __builtin_amdgcn_s_barrier();
            __builtin_amdgcn_sched_barrier(0);
            __builtin_amdgcn_s_setprio(1);
            #pragma unroll
            for (int mi = 0; mi < 4; ++mi)
                #pragma unroll
                for (int ni = 0; ni < 2; ++ni)
                    acc[mi][ni] = __builtin_amdgcn_mfma_f32_32x32x16_f16(af[mi], wf[ni], acc[mi][ni], 0, 0, 0);
            __builtin_amdgcn_s_setprio(0);
        }
    }

    // ---- store f32 partial tile (C/D 32x32: col=l31, row=(reg&3)+8*(reg>>2)+4*lh)
    #pragma unroll
    for (int ni = 0; ni < 2; ++ni) {
        int c    = wn * 64 + ni * 32 + l31;
        int zcol = ((c >> 6) << 10) + jb * 64 + (c & 63);
        #pragma unroll
        for (int mi = 0; mi < 4; ++mi) {
            #pragma unroll
            for (int r = 0; r < 16; ++r) {
                int row = wm * 128 + mi * 32 + (r & 3) + 8 * (r >> 2) + 4 * lh;
                zp[(size_t)(bm0 + row) * NZ + zcol] = acc[mi][ni][r];
            }
        }
    }
}

// ---------------- pass 4: z = zp0 + zp1 + bias, fused LSTM ----------------
__global__ __launch_bounds__(256) void lstm_reduce_kernel(
    const float* __restrict__ zpart, const float* __restrict__ bias,
    const float* __restrict__ c_tm1, float* __restrict__ out)
{
    int b  = blockIdx.x;
    int j4 = threadIdx.x * 4;
    const float* zp0 = zpart + (size_t)b * NZ;
    const float* zp1 = zpart + (size_t)B_SZ * NZ + (size_t)b * NZ;

    f32x4 zg[4];
    #pragma unroll
    for (int g = 0; g < 4; ++g) {
        f32x4 a = *(const f32x4*)(zp0 + g * U_SZ + j4);
        f32x4 c = *(const f32x4*)(zp1 + g * U_SZ + j4);
        f32x4 bb = *(const f32x4*)(bias + g * U_SZ + j4);
        zg[g] = a + c + bb;
    }
    f32x4 cprev = *(const f32x4*)(c_tm1 + (size_t)b * U_SZ + j4);
    f32x4 ho, co;
    #pragma unroll
    for (int e = 0; e < 4; ++e) {
        float ig = 1.f / (1.f + __expf(-zg[0][e]));
        float fg = 1.f / (1.f + __expf(-zg[1][e]));
        float og = 1.f / (1.f + __expf(-zg[3][e]));
        float cn = fg * cprev[e] + ig * tanhf(zg[2][e]);
        co[e] = cn;
        ho[e] = og * tanhf(cn);
    }
    *(f32x4*)(out + (size_t)b * U_SZ + j4) = ho;
    *(f32x4*)(out + (size_t)B_SZ * U_SZ + (size_t)b * U_SZ + j4) = co;
}

extern "C" void kernel_launch(void* const* d_in, const int* in_sizes, int n_in,
                              void* d_out, int out_size, void* d_ws, size_t ws_size,
                              hipStream_t stream) {
    const float* inputs = (const float*)d_in[0];
    const float* h_tm1  = (const float*)d_in[1];
    const float* c_tm1  = (const float*)d_in[2];
    const float* bk     = (const float*)d_in[3];
    const float* brk    = (const float*)d_in[4];
    const float* bias   = (const float*)d_in[5];

    // ws: Ah 36,700,160 | Wth 73,400,320 | zpart 2*33,554,432  (total ~177 MB)
    char*  ws    = (char*)d_ws;
    f16_t* Ah    = (f16_t*)(ws);
    f16_t* Wth   = (f16_t*)(ws + 36700160u);
    float* zpart = (float*)(ws + 36700160u + 73400320u);

    hipFuncSetAttribute((const void*)basis_lstm_gemm_kernel,
                        hipFuncAttributeMaxDynamicSharedMemorySize, SMEM_BYTES);

    hipLaunchKernelGGL(build_a_kernel, dim3(8960), dim3(256), 0, stream,
                       inputs, h_tm1, Ah);
    hipLaunchKernelGGL(transpose_w_kernel, dim3(140, 64), dim3(256), 0, stream,
                       bk, brk, Wth);
    hipLaunchKernelGGL(basis_lstm_gemm_kernel, dim3(256), dim3(512), SMEM_BYTES, stream,
                       Ah, Wth, zpart);
    hipLaunchKernelGGL(lstm_reduce_kernel, dim3(B_SZ), dim3(256), 0, stream,
                       zpart, bias, c_tm1, (float*)d_out);
}